// Round 5
// baseline (401.564 us; speedup 1.0000x reference)
//
#include <hip/hip_runtime.h>

#define DIM 4096
#define KVDIM 1024
#define KVSTRIDE 2048
#define SEQ 2048
#define HEADS 32
#define HD 128

typedef __attribute__((ext_vector_type(8))) short bf16x8;
typedef __attribute__((ext_vector_type(4))) float f32x4;
typedef __attribute__((ext_vector_type(16))) float f32x16;
typedef __attribute__((ext_vector_type(4))) int int4v;

__device__ inline unsigned short f2bf(float f) {
    union { float f; unsigned int u; } v; v.f = f;
    unsigned int r = v.u + 0x7fffu + ((v.u >> 16) & 1u);
    return (unsigned short)(r >> 16);
}
__device__ inline float bf2f(unsigned short h) {
    union { unsigned int u; float f; } v; v.u = ((unsigned int)h) << 16;
    return v.f;
}

// async global->LDS, 16B per lane; LDS dest is wave-uniform base + lane*16
__device__ inline void gld16(const void* g, void* l) {
    __builtin_amdgcn_global_load_lds(
        (const __attribute__((address_space(1))) void*)g,
        (__attribute__((address_space(3))) void*)l, 16, 0, 0);
}

// v_cvt_pk_bf16_f32: lo=bf16(a), hi=bf16(b)
__device__ inline unsigned cvtpk(float a, float b) {
    unsigned r;
    asm("v_cvt_pk_bf16_f32 %0, %1, %2" : "=v"(r) : "v"(a), "v"(b));
    return r;
}

// ---------------- f32 -> bf16 conversion (vectorized) ----------------
__global__ void convert_f32_bf16(const float* __restrict__ in,
                                 unsigned short* __restrict__ out, int n) {
    int i = (blockIdx.x * blockDim.x + threadIdx.x) * 8;
    if (i >= n) return;
    const float4* p = (const float4*)(in + i);
    float4 a = p[0], b = p[1];
    bf16x8 o;
    o[0] = (short)f2bf(a.x); o[1] = (short)f2bf(a.y);
    o[2] = (short)f2bf(a.z); o[3] = (short)f2bf(a.w);
    o[4] = (short)f2bf(b.x); o[5] = (short)f2bf(b.y);
    o[6] = (short)f2bf(b.z); o[7] = (short)f2bf(b.w);
    *(bf16x8*)(out + i) = o;
}

// ---------------- RoPE cos/sin table: [SEQ][64] ----------------
__global__ void rope_table(float* __restrict__ cs, float* __restrict__ sn) {
    int i = blockIdx.x * blockDim.x + threadIdx.x;
    if (i >= SEQ * 64) return;
    int m = i >> 6, f = i & 63;
    float freq = expf(-(float)f * (9.210340371976184f / 64.0f));
    float ang = (float)m * freq;
    float s, c;
    sincosf(ang, &s, &c);
    cs[i] = c; sn[i] = s;
}

// ---------------- RoPE apply in-place (bf16), optional output scale ----------------
__global__ void rope_apply(unsigned short* __restrict__ q, int lppr, int stride, float scale,
                           const float* __restrict__ cs, const float* __restrict__ sn) {
    int i = blockIdx.x * blockDim.x + threadIdx.x;
    int m = i >> lppr;
    int p = i & ((1 << lppr) - 1);
    if (m >= SEQ) return;
    int f = p & 63;
    int col = ((p >> 6) << 7) + (f << 1);
    size_t idx = (size_t)m * stride + col;
    unsigned int u = *(const unsigned int*)&q[idx];
    float xr = bf2f((unsigned short)(u & 0xffffu));
    float xi = bf2f((unsigned short)(u >> 16));
    float c = cs[(m << 6) + f], s = sn[(m << 6) + f];
    float orr = (xr * c - xi * s) * scale;
    float oi  = (xr * s + xi * c) * scale;
    unsigned int w = ((unsigned int)f2bf(oi) << 16) | (unsigned int)f2bf(orr);
    *(unsigned int*)&q[idx] = w;
}

// ---------------- GEMM: C(MxN) = A(MxK bf16) @ W(NxK bf16)^T ----------------
template <bool OUT_BF16>
__global__ __launch_bounds__(256)
void gemm_bt(const unsigned short* __restrict__ A,
             const unsigned short* __restrict__ W,
             void* __restrict__ Cout, int M, int N, int K) {
    __shared__ __align__(16) unsigned short As[128 * 64];
    __shared__ __align__(16) unsigned short Ws[128 * 64];

    int nwg = gridDim.x * gridDim.y;
    int wg = blockIdx.y * gridDim.x + blockIdx.x;
    int cpx = nwg >> 3;
    wg = (wg & 7) * cpx + (wg >> 3);
    int bx = wg % gridDim.x, by = wg / gridDim.x;
    int brow = by * 128, bcol = bx * 128;

    int tid = threadIdx.x, lane = tid & 63, wid = tid >> 6;
    int wr = wid >> 1, wc = wid & 1, l15 = lane & 15, lq = lane >> 4;

    f32x4 acc[4][4] = {};

    for (int bk = 0; bk < K; bk += 64) {
        #pragma unroll
        for (int it = 0; it < 4; ++it) {
            int slot = it * 256 + wid * 64 + lane;
            int r = slot >> 3, g = slot & 7;
            gld16(&A[(size_t)(brow + r) * K + bk + ((g ^ (r & 7)) << 3)],
                  &As[(it * 256 + wid * 64) * 8]);
        }
        #pragma unroll
        for (int it = 0; it < 4; ++it) {
            int slot = it * 256 + wid * 64 + lane;
            int r = slot >> 3, g = slot & 7;
            gld16(&W[(size_t)(bcol + r) * K + bk + ((g ^ (r & 7)) << 3)],
                  &Ws[(it * 256 + wid * 64) * 8]);
        }
        __syncthreads();

        #pragma unroll
        for (int kk = 0; kk < 64; kk += 32) {
            int gb = (kk >> 3) + lq;
            bf16x8 af[4], bfr[4];
            #pragma unroll
            for (int m = 0; m < 4; ++m) {
                int r = wr * 64 + m * 16 + l15;
                af[m] = *(const bf16x8*)&As[r * 64 + ((gb ^ (r & 7)) << 3)];
            }
            #pragma unroll
            for (int n = 0; n < 4; ++n) {
                int r = wc * 64 + n * 16 + l15;
                bfr[n] = *(const bf16x8*)&Ws[r * 64 + ((gb ^ (r & 7)) << 3)];
            }
            #pragma unroll
            for (int m = 0; m < 4; ++m)
                #pragma unroll
                for (int n = 0; n < 4; ++n)
                    acc[m][n] = __builtin_amdgcn_mfma_f32_16x16x32_bf16(
                        af[m], bfr[n], acc[m][n], 0, 0, 0);
        }
        __syncthreads();
    }

    #pragma unroll
    for (int m = 0; m < 4; ++m) {
        #pragma unroll
        for (int n = 0; n < 4; ++n) {
            int row0 = brow + wr * 64 + m * 16 + lq * 4;
            int col = bcol + wc * 64 + n * 16 + l15;
            #pragma unroll
            for (int r = 0; r < 4; ++r) {
                if (OUT_BF16)
                    ((unsigned short*)Cout)[(size_t)(row0 + r) * N + col] = f2bf(acc[m][n][r]);
                else
                    ((float*)Cout)[(size_t)(row0 + r) * N + col] = acc[m][n][r];
            }
        }
    }
}

// ---------------- Flash attention: 32x32 swapped-QK^T + 2-phase pipeline ----
// 4 waves x 32 q-rows (QBLK=128), KBLK=64, double-buffered K/V tiles.
// Per iter: issue next-tile K (global_load_lds) + V (global->reg) BEFORE
// compute; vmcnt(0) + late ds_write of V after compute (T14); one barrier.
// S^T = mfma(K,Q): q = lane&31 -> in-register softmax. setprio on MFMA (T5).
__global__ __launch_bounds__(256)
void attn_kernel(const unsigned short* __restrict__ Q,
                 const unsigned short* __restrict__ KV,
                 unsigned short* __restrict__ O) {
    __shared__ __align__(16) unsigned short ks[2][64 * 128];   // 32 KB
    __shared__ __align__(16) unsigned short vt[2][128][66];    // 33 KB

    int h = blockIdx.x;
    int yy = (gridDim.y - 1) - blockIdx.y;   // LPT: longest blocks first
    int q0 = yy * 128;
    int kvh = h >> 2;
    int tid = threadIdx.x, lane = tid & 63, wid = tid >> 6;
    int l31 = lane & 31, l5 = lane >> 5;
    int qw0 = q0 + wid * 32;

    // Q fragments (B-operand): qf[k8] = Q[qw0+l31][h*128 + k8*16 + l5*8 ..]
    bf16x8 qf[8];
    #pragma unroll
    for (int k8 = 0; k8 < 8; ++k8)
        qf[k8] = *(const bf16x8*)&Q[(size_t)(qw0 + l31) * DIM + h * HD + k8 * 16 + l5 * 8];

    f32x16 o_acc[4] = {};
    float m_run = -1e30f, l_run = 0.0f;

    // V staging decomposition: thread stages 4 kv-rows x 8 d's
    int k4 = tid >> 4;            // [0,16) -> kv = k4*4 .. +4
    int d0 = (tid & 15) * 8;      // [0,128)

    const unsigned short* Kbase = KV + kvh * HD;
    const unsigned short* Vbase = KV + KVDIM + kvh * HD;

    int ntiles = (q0 + 128) >> 6;
    bf16x8 vr[4];

    // ---- prologue: stage tile 0 ----
    #pragma unroll
    for (int it = 0; it < 4; ++it) {
        int slot = it * 256 + wid * 64 + lane;
        int r = slot >> 4, g = slot & 15;
        gld16(&Kbase[(size_t)r * KVSTRIDE + ((g ^ (r & 7)) << 3)],
              &ks[0][(it * 256 + wid * 64) * 8]);
    }
    #pragma unroll
    for (int j = 0; j < 4; ++j)
        vr[j] = *(const bf16x8*)&Vbase[(size_t)(k4 * 4 + j) * KVSTRIDE + d0];
    asm volatile("s_waitcnt vmcnt(0)" ::: "memory");
    #pragma unroll
    for (int j = 0; j < 8; ++j) {
        unsigned lo = ((unsigned)(unsigned short)vr[1][j] << 16) | (unsigned)(unsigned short)vr[0][j];
        unsigned hi = ((unsigned)(unsigned short)vr[3][j] << 16) | (unsigned)(unsigned short)vr[2][j];
        *(unsigned*)&vt[0][d0 + j][k4 * 4]     = lo;
        *(unsigned*)&vt[0][d0 + j][k4 * 4 + 2] = hi;
    }
    __syncthreads();

    for (int t = 0; t < ntiles; ++t) {
        int b = t & 1;
        int kv0 = t * 64;
        bool pre = (t + 1 < ntiles);
        // ---- issue next-tile loads (fire-and-forget K, reg-carried V) ----
        if (pre) {
            int kvn = kv0 + 64;
            #pragma unroll
            for (int it = 0; it < 4; ++it) {
                int slot = it * 256 + wid * 64 + lane;
                int r = slot >> 4, g = slot & 15;
                gld16(&Kbase[(size_t)(kvn + r) * KVSTRIDE + ((g ^ (r & 7)) << 3)],
                      &ks[b ^ 1][(it * 256 + wid * 64) * 8]);
            }
            #pragma unroll
            for (int j = 0; j < 4; ++j)
                vr[j] = *(const bf16x8*)&Vbase[(size_t)(kvn + k4 * 4 + j) * KVSTRIDE + d0];
        }

        // ---- compute on buffer b ----
        if (kv0 <= qw0 + 31) {
            #pragma unroll
            for (int sub = 0; sub < 2; ++sub) {
                int kvs = kv0 + sub * 32;
                if (kvs > qw0 + 31) continue;   // wave-uniform: fully masked
                // S^T = K @ Q^T : D row = kv, col = q
                f32x16 s = {};
                __builtin_amdgcn_s_setprio(1);
                #pragma unroll
                for (int k8 = 0; k8 < 8; ++k8) {
                    int r = sub * 32 + l31;
                    bf16x8 kf = *(const bf16x8*)&ks[b][r * 128 + (((k8 * 2 + l5) ^ (r & 7)) << 3)];
                    s = __builtin_amdgcn_mfma_f32_32x32x16_bf16(kf, qf[k8], s, 0, 0, 0);
                }
                __builtin_amdgcn_s_setprio(0);
                // causal mask: kv = kvs + (r&3)+8*(r>>2)+4*l5 ; q = qw0 + l31
                if (kvs + 31 > qw0) {
                    #pragma unroll
                    for (int r = 0; r < 16; ++r) {
                        int kv = kvs + (r & 3) + ((r >> 2) << 3) + l5 * 4;
                        if (kv > qw0 + l31) s[r] = -1e30f;
                    }
                }
                // online softmax, q-local (1 cross-lane op)
                float mx = s[0];
                #pragma unroll
                for (int r = 1; r < 16; ++r) mx = fmaxf(mx, s[r]);
                mx = fmaxf(mx, __shfl_xor(mx, 32));
                bool need = mx > m_run + 8.0f;   // defer-max, log2 domain
                if (__any((int)need)) {
                    float mn = fmaxf(m_run, mx);
                    float al = exp2f(m_run - mn);
                    m_run = mn;
                    l_run *= al;
                    #pragma unroll
                    for (int r = 0; r < 16; ++r) {
                        int qlr = (r & 3) + ((r >> 2) << 3) + l5 * 4;
                        float alO = __shfl(al, qlr, 32);
                        #pragma unroll
                        for (int t32 = 0; t32 < 4; ++t32) o_acc[t32][r] *= alO;
                    }
                }
                #pragma unroll
                for (int r = 0; r < 16; ++r) {
                    float p = exp2f(s[r] - m_run);
                    l_run += p;
                    s[r] = p;
                }
                // pack P -> A-frags: bit5 exchange only
                bf16x8 pa[2];
                #pragma unroll
                for (int kk1 = 0; kk1 < 2; ++kk1) {
                    unsigned u0 = cvtpk(s[kk1 * 8 + 0], s[kk1 * 8 + 1]);
                    unsigned u1 = cvtpk(s[kk1 * 8 + 2], s[kk1 * 8 + 3]);
                    unsigned u2 = cvtpk(s[kk1 * 8 + 4], s[kk1 * 8 + 5]);
                    unsigned u3 = cvtpk(s[kk1 * 8 + 6], s[kk1 * 8 + 7]);
                    unsigned t0 = (unsigned)__shfl_xor((int)(l5 ? u0 : u2), 32);
                    unsigned t1 = (unsigned)__shfl_xor((int)(l5 ? u1 : u3), 32);
                    int4v w;
                    w.x = (int)(l5 ? t0 : u0);
                    w.y = (int)(l5 ? t1 : u1);
                    w.z = (int)(l5 ? u2 : t0);
                    w.w = (int)(l5 ? u3 : t1);
                    pa[kk1] = __builtin_bit_cast(bf16x8, w);
                }
                // PV: B-frag = vt[d = t32*32+l31][kv = sub*32 + kk1*16 + l5*8 ..]
                __builtin_amdgcn_s_setprio(1);
                #pragma unroll
                for (int t32 = 0; t32 < 4; ++t32) {
                    #pragma unroll
                    for (int kk1 = 0; kk1 < 2; ++kk1) {
                        const unsigned short* vrow =
                            &vt[b][t32 * 32 + l31][sub * 32 + kk1 * 16 + l5 * 8];
                        int4v w;
                        w.x = *(const int*)&vrow[0];
                        w.y = *(const int*)&vrow[2];
                        w.z = *(const int*)&vrow[4];
                        w.w = *(const int*)&vrow[6];
                        o_acc[t32] = __builtin_amdgcn_mfma_f32_32x32x16_bf16(
                            pa[kk1], __builtin_bit_cast(bf16x8, w), o_acc[t32], 0, 0, 0);
                    }
                }
                __builtin_amdgcn_s_setprio(0);
            }
        }

        // ---- drain loads, late V write into next buffer, single barrier ----
        if (pre) {
            asm volatile("s_waitcnt vmcnt(0)" ::: "memory");
            #pragma unroll
            for (int j = 0; j < 8; ++j) {
                unsigned lo = ((unsigned)(unsigned short)vr[1][j] << 16) | (unsigned)(unsigned short)vr[0][j];
                unsigned hi = ((unsigned)(unsigned short)vr[3][j] << 16) | (unsigned)(unsigned short)vr[2][j];
                *(unsigned*)&vt[b ^ 1][d0 + j][k4 * 4]     = lo;
                *(unsigned*)&vt[b ^ 1][d0 + j][k4 * 4 + 2] = hi;
            }
        }
        __syncthreads();
    }

    // epilogue: l over lane-halves, redistribute to O layout, store
    float l_tot = l_run + __shfl_xor(l_run, 32);
    float rinv = __builtin_amdgcn_rcpf(l_tot);
    #pragma unroll
    for (int r = 0; r < 16; ++r) {
        int qlr = (r & 3) + ((r >> 2) << 3) + l5 * 4;
        float rl = __shfl(rinv, qlr, 32);
        #pragma unroll
        for (int t32 = 0; t32 < 4; ++t32)
            O[(size_t)(qw0 + qlr) * DIM + h * HD + t32 * 32 + l31] =
                f2bf(o_acc[t32][r] * rl);
    }
}

// ---------------- host ----------------
extern "C" void kernel_launch(void* const* d_in, const int* in_sizes, int n_in,
                              void* d_out, int out_size, void* d_ws, size_t ws_size,
                              hipStream_t stream) {
    const float* x  = (const float*)d_in[0];
    const float* wq = (const float*)d_in[2];
    const float* wk = (const float*)d_in[3];
    const float* wv = (const float*)d_in[4];
    const float* wo = (const float*)d_in[5];
    float* out = (float*)d_out;

    char* ws = (char*)d_ws;
    unsigned short* xb  = (unsigned short*)(ws);               // 16 MiB
    unsigned short* qb  = (unsigned short*)(ws + 16777216);    // 16 MiB
    unsigned short* kvb = (unsigned short*)(ws + 33554432);    //  8 MiB (K|V, stride 2048)
    unsigned short* ab  = (unsigned short*)(ws + 41943040);    // 16 MiB
    float* cs = (float*)(ws + 58720256);
    float* sn = cs + SEQ * 64;
    unsigned short* wscratch = (unsigned short*)d_out;         // weight staging
    unsigned short* wob = (unsigned short*)(ws);               // after attn: xb dead

    const float SCALE2 = 0.08838834764831845f * 1.4426950408889634f;

    convert_f32_bf16<<<SEQ * DIM / 2048, 256, 0, stream>>>(x, xb, SEQ * DIM);
    rope_table<<<SEQ * 64 / 256, 256, 0, stream>>>(cs, sn);

    convert_f32_bf16<<<DIM * DIM / 2048, 256, 0, stream>>>(wq, wscratch, DIM * DIM);
    gemm_bt<true><<<dim3(DIM / 128, SEQ / 128), 256, 0, stream>>>(xb, wscratch, qb, SEQ, DIM, DIM);

    convert_f32_bf16<<<KVDIM * DIM / 2048, 256, 0, stream>>>(wk, wscratch, KVDIM * DIM);
    convert_f32_bf16<<<KVDIM * DIM / 2048, 256, 0, stream>>>(wv, wscratch + (size_t)KVDIM * DIM, KVDIM * DIM);
    gemm_bt<true><<<dim3(KVSTRIDE / 128, SEQ / 128), 256, 0, stream>>>(xb, wscratch, kvb, SEQ, KVSTRIDE, DIM);

    rope_apply<<<SEQ * (DIM / 2) / 256, 256, 0, stream>>>(qb, 11, DIM, SCALE2, cs, sn);
    rope_apply<<<SEQ * (KVDIM / 2) / 256, 256, 0, stream>>>(kvb, 9, KVSTRIDE, 1.0f, cs, sn);

    attn_kernel<<<dim3(HEADS, SEQ / 128), 256, 0, stream>>>(qb, kvb, ab);

    convert_f32_bf16<<<DIM * DIM / 2048, 256, 0, stream>>>(wo, wob, DIM * DIM);
    gemm_bt<false><<<dim3(DIM / 128, SEQ / 128), 256, 0, stream>>>(ab, wob, out, SEQ, DIM, DIM);
}